// Round 7
// baseline (372.132 us; speedup 1.0000x reference)
//
#include <hip/hip_runtime.h>
#include <hip/hip_bf16.h>
#include <hip/hip_cooperative_groups.h>

namespace cg = cooperative_groups;

#define N_NODES 50000
#define N_EDGES 800000
#define DIM 64
#define NHEAD 2
#define HD 128     // NHEAD * DIM
#define NCOL 448   // 128 q + 128 k + 128 vc + 64 skipc
#define NPAD 50048 // xb rows padded to multiple of 64

#define SCAN_B 196   // ceil(50000/256)
#define CSR_BLOCKS 256
#define CSR_THREADS 65536  // 256*256

typedef short bf16x8 __attribute__((ext_vector_type(8)));
typedef float f32x16 __attribute__((ext_vector_type(16)));

__device__ __forceinline__ float bflo(unsigned u) { return __uint_as_float(u << 16); }
__device__ __forceinline__ float bfhi(unsigned u) { return __uint_as_float(u & 0xffff0000u); }
__device__ __forceinline__ unsigned short f2bf(float f) {
    unsigned u = __float_as_uint(f);
    unsigned r = (u + 0x7fffu + ((u >> 16) & 1u)) >> 16;   // RNE
    return (unsigned short)r;
}

// ---------------- build combined transposed weight WallT[448][64] bf16 + ball[448] ----
// cols 0..127: 0.125*Wq | 128..255: Wk | 256..383: Wvc=Wv@Wc per head | 384..447: Wskip@Wc
__global__ __launch_bounds__(64) void k_prep(
    const float* __restrict__ Wq, const float* __restrict__ bq,
    const float* __restrict__ Wk, const float* __restrict__ bk,
    const float* __restrict__ Wv, const float* __restrict__ bv,
    const float* __restrict__ Wskip, const float* __restrict__ bskip,
    const float* __restrict__ Wc, const float* __restrict__ bc,
    unsigned short* __restrict__ WallT, float* __restrict__ ball,
    double* __restrict__ stats)
{
    const int j = blockIdx.x;    // output column 0..447
    const int d = threadIdx.x;   // k index 0..63
    if (j == 0 && d == 0) { stats[0] = 0.0; stats[1] = 0.0; }
    float w, b;
    if (j < 128) {
        w = Wq[d * HD + j] * 0.125f;
        b = bq[j] * 0.125f;
    } else if (j < 256) {
        int jj = j - 128;
        w = Wk[d * HD + jj];
        b = bk[jj];
    } else if (j < 384) {
        int jj = j - 256;
        int h = jj >> 6, jc = jj & 63;
        float s = 0.f, sb = 0.f;
        for (int c = 0; c < 64; c++) {
            float wc = Wc[(h * 64 + c) * DIM + jc];
            s  += Wv[d * HD + h * 64 + c] * wc;
            sb += bv[h * 64 + c] * wc;
        }
        w = s; b = sb;
    } else {
        int jj = j - 384;
        float s = 0.f, sb = bc[jj];
        for (int c = 0; c < HD; c++) {
            float wc = Wc[c * DIM + jj];
            s  += Wskip[d * HD + c] * wc;
            sb += bskip[c] * wc;
        }
        w = s; b = sb;
    }
    WallT[j * 64 + d] = f2bf(w);
    if (d == 0) ball[j] = b;
}

// ---------------- cooperative CSR build + x->bf16 cast ----------------
// 256 blocks x 256 threads. Phases separated by grid.sync():
//  0: zero deg
//  1: cast x (800000 float4) + histogram with per-edge rank capture
//  2a: per-scan-block degree sums (blocks 0..195)
//  2b: exclusive scan -> rowstart
//  3: elist[rowstart[d] + rank[e]] = src   (no atomics)
__global__ __launch_bounds__(256) void k_csr(
    const float* __restrict__ x, const int* __restrict__ ei,
    unsigned short* __restrict__ xb, int* __restrict__ deg,
    int* __restrict__ rank, int* __restrict__ bsum,
    int* __restrict__ rowstart, int* __restrict__ elist)
{
    cg::grid_group grid = cg::this_grid();
    const int t = threadIdx.x;
    const int b = blockIdx.x;
    const int gid = b * 256 + t;

    // phase 0: zero degree histogram
    if (gid < N_NODES) deg[gid] = 0;
    grid.sync();

    // phase 1: cast + histogram (rank = old count)
    for (int i = gid; i < N_EDGES; i += CSR_THREADS) {
        rank[i] = atomicAdd(&deg[ei[N_EDGES + i]], 1);
        float4 xv = ((const float4*)x)[i];   // 800000 float4 == N_NODES*64/4
        ushort4 o;
        o.x = f2bf(xv.x); o.y = f2bf(xv.y); o.z = f2bf(xv.z); o.w = f2bf(xv.w);
        ((ushort4*)xb)[i] = o;
    }
    grid.sync();

    // phase 2a: per-block degree sums (blocks 0..SCAN_B-1, 256 nodes each)
    __shared__ int sd4[4];
    if (b < SCAN_B) {
        int idx = b * 256 + t;
        int d = (idx < N_NODES) ? deg[idx] : 0;
        int s = d;
#pragma unroll
        for (int off = 32; off > 0; off >>= 1) s += __shfl_down(s, off);
        if ((t & 63) == 0) sd4[t >> 6] = s;
        __syncthreads();
        if (t == 0) bsum[b] = sd4[0] + sd4[1] + sd4[2] + sd4[3];
    }
    grid.sync();

    // phase 2b: block offset + local exclusive scan -> rowstart
    __shared__ int swv[4];
    __shared__ int sd[256];
    if (b < SCAN_B) {
        int v = (t < b) ? bsum[t] : 0;   // b <= 195 < 256
#pragma unroll
        for (int off = 32; off > 0; off >>= 1) v += __shfl_down(v, off);
        if ((t & 63) == 0) swv[t >> 6] = v;
        int idx = b * 256 + t;
        int d = (idx < N_NODES) ? deg[idx] : 0;
        sd[t] = d;
        __syncthreads();
        int base = swv[0] + swv[1] + swv[2] + swv[3];
        for (int off = 1; off < 256; off <<= 1) {
            int add = (t >= off) ? sd[t - off] : 0;
            __syncthreads();
            sd[t] += add;
            __syncthreads();
        }
        if (idx < N_NODES) rowstart[idx] = base + sd[t] - d;
    }
    grid.sync();

    // phase 3: scatter edges into buckets (atomic-free)
    for (int i = gid; i < N_EDGES; i += CSR_THREADS) {
        int d = ei[N_EDGES + i];
        elist[rowstart[d] + rank[i]] = ei[i];
    }
}

// ---------------- MFMA projection GEMM: [50048 x 64] @ [64 x 448] ----------------
// C/D: col=lane&31, row=(reg&3)+8*(reg>>2)+4*(lane>>5)
__global__ __launch_bounds__(256) void k_proj_mfma(
    const unsigned short* __restrict__ xb, const unsigned short* __restrict__ WallT,
    const float* __restrict__ ball,
    float* __restrict__ q, unsigned short* __restrict__ kv, float* __restrict__ skipc)
{
    const int w = threadIdx.x >> 6;
    const int lane = threadIdx.x & 63;
    const int col = lane & 31;
    const int khalf = lane >> 5;
    const int n0 = blockIdx.x * 64 + (w >> 1) * 32;
    const int ct0 = (w & 1) * 7;
    const int rowbase = 4 * khalf;

    bf16x8 afrag[4];
    const unsigned short* ap = xb + (size_t)(n0 + col) * 64 + khalf * 8;
#pragma unroll
    for (int kk = 0; kk < 4; kk++)
        afrag[kk] = *((const bf16x8*)(ap + kk * 16));

    for (int t = 0; t < 7; t++) {
        const int ct = ct0 + t;
        const int gc = ct * 32 + col;
        const float b = ball[gc];
        f32x16 acc;
#pragma unroll
        for (int r = 0; r < 16; r++) acc[r] = b;
        const unsigned short* bp = WallT + (size_t)gc * 64 + khalf * 8;
#pragma unroll
        for (int kk = 0; kk < 4; kk++) {
            bf16x8 bfrag = *((const bf16x8*)(bp + kk * 16));
            acc = __builtin_amdgcn_mfma_f32_32x32x16_bf16(afrag[kk], bfrag, acc, 0, 0, 0);
        }
        if (gc < 128) {
#pragma unroll
            for (int r = 0; r < 16; r++) {
                int node = n0 + (r & 3) + 8 * (r >> 2) + rowbase;
                if (node < N_NODES) q[(size_t)node * HD + gc] = acc[r];
            }
        } else if (gc < 256) {
#pragma unroll
            for (int r = 0; r < 16; r++) {
                int node = n0 + (r & 3) + 8 * (r >> 2) + rowbase;
                if (node < N_NODES) kv[(size_t)node * 256 + (gc - 128)] = f2bf(acc[r]);
            }
        } else if (gc < 384) {
#pragma unroll
            for (int r = 0; r < 16; r++) {
                int node = n0 + (r & 3) + 8 * (r >> 2) + rowbase;
                if (node < N_NODES) kv[(size_t)node * 256 + 128 + (gc - 256)] = f2bf(acc[r]);
            }
        } else {
#pragma unroll
            for (int r = 0; r < 16; r++) {
                int node = n0 + (r & 3) + 8 * (r >> 2) + rowbase;
                if (node < N_NODES) skipc[(size_t)node * DIM + (gc - 384)] = acc[r];
            }
        }
    }
}

// ---------------- fused attention: 8-edge-parallel softmax-aggregate + skipc + stats --
__global__ __launch_bounds__(256) void k_attn(
    const float* __restrict__ q, const unsigned short* __restrict__ kv,
    const float* __restrict__ skipc,
    const int* __restrict__ rowstart, const int* __restrict__ deg,
    const int* __restrict__ elist,
    float* __restrict__ out2, float* __restrict__ partials)
{
    const int w = threadIdx.x >> 6;
    const int lane = threadIdx.x & 63;
    const int g = lane >> 3;   // edge group 0..7
    const int j = lane & 7;    // channels 8j..8j+7
    const int n = blockIdx.x * 4 + w;
    const float4* qp = (const float4*)(q + (size_t)n * HD);
    const float4 qa = qp[2 * j],      qb = qp[2 * j + 1];      // head0
    const float4 qc = qp[16 + 2 * j], qd = qp[17 + 2 * j];     // head1
    float acc0[8], acc1[8];
#pragma unroll
    for (int i = 0; i < 8; i++) { acc0[i] = 0.f; acc1[i] = 0.f; }
    float l0 = 0.f, l1 = 0.f;
    const int start = rowstart[n];
    const int end = start + deg[n];
    for (int b0 = start; b0 < end; b0 += 8) {
        int idx = b0 + g;
        bool valid = idx < end;
        int s = elist[valid ? idx : start];
        const uint4* kp = (const uint4*)(kv + (size_t)s * 256);
        uint4 K0 = kp[j], K1 = kp[8 + j];
        uint4 V0 = kp[16 + j], V1 = kp[24 + j];
        float p0 = qa.x * bflo(K0.x) + qa.y * bfhi(K0.x)
                 + qa.z * bflo(K0.y) + qa.w * bfhi(K0.y)
                 + qb.x * bflo(K0.z) + qb.y * bfhi(K0.z)
                 + qb.z * bflo(K0.w) + qb.w * bfhi(K0.w);
        float p1 = qc.x * bflo(K1.x) + qc.y * bfhi(K1.x)
                 + qc.z * bflo(K1.y) + qc.w * bfhi(K1.y)
                 + qd.x * bflo(K1.z) + qd.y * bfhi(K1.z)
                 + qd.z * bflo(K1.w) + qd.w * bfhi(K1.w);
#pragma unroll
        for (int off = 1; off < 8; off <<= 1) {
            p0 += __shfl_xor(p0, off, 64);
            p1 += __shfl_xor(p1, off, 64);
        }
        float w0 = valid ? __expf(p0) : 0.f;
        float w1 = valid ? __expf(p1) : 0.f;
        l0 += w0; l1 += w1;
        acc0[0] += w0 * bflo(V0.x); acc0[1] += w0 * bfhi(V0.x);
        acc0[2] += w0 * bflo(V0.y); acc0[3] += w0 * bfhi(V0.y);
        acc0[4] += w0 * bflo(V0.z); acc0[5] += w0 * bfhi(V0.z);
        acc0[6] += w0 * bflo(V0.w); acc0[7] += w0 * bfhi(V0.w);
        acc1[0] += w1 * bflo(V1.x); acc1[1] += w1 * bfhi(V1.x);
        acc1[2] += w1 * bflo(V1.y); acc1[3] += w1 * bfhi(V1.y);
        acc1[4] += w1 * bflo(V1.z); acc1[5] += w1 * bfhi(V1.z);
        acc1[6] += w1 * bflo(V1.w); acc1[7] += w1 * bfhi(V1.w);
    }
#pragma unroll
    for (int off = 8; off < 64; off <<= 1) {
        l0 += __shfl_xor(l0, off, 64);
        l1 += __shfl_xor(l1, off, 64);
#pragma unroll
        for (int i = 0; i < 8; i++) {
            acc0[i] += __shfl_xor(acc0[i], off, 64);
            acc1[i] += __shfl_xor(acc1[i], off, 64);
        }
    }
    if (g == 0) {
        float inv0 = 1.f / (l0 + 1e-16f), inv1 = 1.f / (l1 + 1e-16f);
        const float4* sk = (const float4*)(skipc + (size_t)n * DIM);
        float4 sa = sk[2 * j], sb = sk[2 * j + 1];
        float o[8];
        o[0] = acc0[0] * inv0 + acc1[0] * inv1 + sa.x;
        o[1] = acc0[1] * inv0 + acc1[1] * inv1 + sa.y;
        o[2] = acc0[2] * inv0 + acc1[2] * inv1 + sa.z;
        o[3] = acc0[3] * inv0 + acc1[3] * inv1 + sa.w;
        o[4] = acc0[4] * inv0 + acc1[4] * inv1 + sb.x;
        o[5] = acc0[5] * inv0 + acc1[5] * inv1 + sb.y;
        o[6] = acc0[6] * inv0 + acc1[6] * inv1 + sb.z;
        o[7] = acc0[7] * inv0 + acc1[7] * inv1 + sb.w;
        float4 r0 = {o[0], o[1], o[2], o[3]}, r1 = {o[4], o[5], o[6], o[7]};
        float4* op = (float4*)(out2 + (size_t)n * DIM);
        op[2 * j] = r0; op[2 * j + 1] = r1;
        float s_ = 0.f, ss = 0.f;
#pragma unroll
        for (int i = 0; i < 8; i++) { s_ += o[i]; ss += o[i] * o[i]; }
#pragma unroll
        for (int off = 1; off < 8; off <<= 1) {
            s_ += __shfl_xor(s_, off, 64);
            ss += __shfl_xor(ss, off, 64);
        }
        if (j == 0) { partials[n * 2 + 0] = s_; partials[n * 2 + 1] = ss; }
    }
}

// ---------------- multi-block reduction of partials -> stats (f64 atomics) ----------
#define RED_BLOCKS 100
__global__ __launch_bounds__(256) void k_reduce(
    const float* __restrict__ partials, double* __restrict__ stats)
{
    double s = 0.0, ss = 0.0;
    for (int i = blockIdx.x * 256 + threadIdx.x; i < N_NODES; i += RED_BLOCKS * 256) {
        s  += (double)partials[i * 2 + 0];
        ss += (double)partials[i * 2 + 1];
    }
#pragma unroll
    for (int off = 32; off > 0; off >>= 1) {
        s  += __shfl_down(s, off);
        ss += __shfl_down(ss, off);
    }
    __shared__ double sd[8];
    int wave = threadIdx.x >> 6;
    if ((threadIdx.x & 63) == 0) { sd[wave * 2] = s; sd[wave * 2 + 1] = ss; }
    __syncthreads();
    if (threadIdx.x == 0) {
        double S = 0.0, SS = 0.0;
        for (int w = 0; w < 4; w++) { S += sd[w * 2]; SS += sd[w * 2 + 1]; }
        atomicAdd(&stats[0], S);
        atomicAdd(&stats[1], SS);
    }
}

// ---------------- graph layernorm + gamma/beta (in-place on d_out) ----------------
__global__ __launch_bounds__(256) void k_norm(
    float* __restrict__ out, const double* __restrict__ stats,
    const float* __restrict__ gamma, const float* __restrict__ beta)
{
    int i = blockIdx.x * blockDim.x + threadIdx.x;
    if (i >= N_NODES * DIM) return;
    const double cnt = (double)N_NODES * (double)DIM;
    double mean = stats[0] / cnt;
    double var  = stats[1] / cnt - mean * mean;
    if (var < 0.0) var = 0.0;
    float stdv = (float)sqrt(var);
    float inv  = 1.0f / (stdv + 1e-5f);
    int j = i & (DIM - 1);
    out[i] = (out[i] - (float)mean) * inv * gamma[j] + beta[j];
}

extern "C" void kernel_launch(void* const* d_in, const int* in_sizes, int n_in,
                              void* d_out, int out_size, void* d_ws, size_t ws_size,
                              hipStream_t stream) {
    const float* x     = (const float*)d_in[0];
    const int*   ei    = (const int*)d_in[1];
    const float* Wq    = (const float*)d_in[2];
    const float* bq    = (const float*)d_in[3];
    const float* Wk    = (const float*)d_in[4];
    const float* bk    = (const float*)d_in[5];
    const float* Wv    = (const float*)d_in[6];
    const float* bv    = (const float*)d_in[7];
    const float* Wsk   = (const float*)d_in[8];
    const float* bsk   = (const float*)d_in[9];
    const float* Wc    = (const float*)d_in[10];
    const float* bc    = (const float*)d_in[11];
    const float* gamma = (const float*)d_in[12];
    const float* beta  = (const float*)d_in[13];
    float* out = (float*)d_out;

    // ws layout
    float* ws = (float*)d_ws;
    const size_t NF = (size_t)N_NODES * HD;               // 6.4M floats
    float* q = ws;                                        // [N,128] f32
    unsigned short* kv = (unsigned short*)(ws + NF);      // [N,256] bf16 (k|vc)
    float* skipc = ws + 2 * NF;                           // [N,64]  f32
    unsigned short* xb = (unsigned short*)(skipc + (size_t)N_NODES * DIM); // [NPAD,64] bf16
    unsigned short* WallT = xb + (size_t)NPAD * 64;       // [448,64] bf16
    float* ball   = (float*)(WallT + NCOL * 64);          // [448]
    int* deg      = (int*)(ball + NCOL);                  // [N]
    int* rowstart = deg + N_NODES;                        // [N]
    int* bsum     = rowstart + N_NODES;                   // [256]
    int* rank     = bsum + 256;                           // [E]
    int* elist    = rank + N_EDGES;                       // [E]
    float* parts  = (float*)(elist + N_EDGES);            // [N,2]
    double* stats = (double*)(parts + (size_t)N_NODES * 2);

    hipLaunchKernelGGL(k_prep, dim3(NCOL), dim3(64), 0, stream,
                       Wq, bq, Wk, bk, Wv, bv, Wsk, bsk, Wc, bc, WallT, ball, stats);
    {
        void* args[] = {(void*)&x, (void*)&ei, (void*)&xb, (void*)&deg,
                        (void*)&rank, (void*)&bsum, (void*)&rowstart, (void*)&elist};
        hipLaunchCooperativeKernel((const void*)k_csr, dim3(CSR_BLOCKS), dim3(256),
                                   args, 0, stream);
    }
    hipLaunchKernelGGL(k_proj_mfma, dim3(NPAD / 64), dim3(256), 0, stream,
                       xb, WallT, ball, q, kv, skipc);
    hipLaunchKernelGGL(k_attn, dim3(N_NODES / 4), dim3(256), 0, stream,
                       q, kv, skipc, rowstart, deg, elist, out, parts);
    hipLaunchKernelGGL(k_reduce, dim3(RED_BLOCKS), dim3(256), 0, stream, parts, stats);
    hipLaunchKernelGGL(k_norm, dim3((N_NODES * DIM + 255) / 256), dim3(256), 0, stream,
                       out, stats, gamma, beta);
}